// Round 1
// baseline (387.569 us; speedup 1.0000x reference)
//
#include <hip/hip_runtime.h>
#include <hip/hip_bf16.h>

#define BB 2
#define TT 2048
#define CCH 1024
#define NHH 16
#define HDD 64
#define M_TOK (BB*TT)      // 4096
#define N_QKV (3*CCH)      // 3072

typedef __attribute__((ext_vector_type(8))) short bf16x8;
typedef __attribute__((ext_vector_type(4))) float f32x4;
typedef unsigned short u16;
typedef unsigned int u32;

__device__ __forceinline__ u16 f2bf(float f) {
    union { float f; u32 u; } v; v.f = f;
    u32 u = v.u;
    u32 r = (u + 0x7FFFu + ((u >> 16) & 1u)) >> 16;
    return (u16)r;
}

__device__ __forceinline__ void async_copy16(const void* g, void* l) {
    __builtin_amdgcn_global_load_lds((__attribute__((address_space(1))) void*)g,
                                     (__attribute__((address_space(3))) void*)l,
                                     16, 0, 0);
}

// ---------------- pre-pass kernels ----------------

__global__ __launch_bounds__(256) void cast_bf16_kernel(
    const float* __restrict__ src, u16* __restrict__ dst, int n4) {
    int i = blockIdx.x * 256 + threadIdx.x;
    if (i < n4) {
        float4 f = ((const float4*)src)[i];
        ushort4 o;
        o.x = f2bf(f.x); o.y = f2bf(f.y); o.z = f2bf(f.z); o.w = f2bf(f.w);
        ((ushort4*)dst)[i] = o;
    }
}

// src [R][Cn] fp32 -> dst [Cn][R] bf16
__global__ __launch_bounds__(256) void transpose_bf16_kernel(
    const float* __restrict__ src, u16* __restrict__ dst, int R, int Cn) {
    __shared__ float tile[32][33];
    int c0 = blockIdx.x * 32, r0 = blockIdx.y * 32;
    int tx = threadIdx.x, ty = threadIdx.y;
#pragma unroll
    for (int i = ty; i < 32; i += 8)
        tile[i][tx] = src[(size_t)(r0 + i) * Cn + c0 + tx];
    __syncthreads();
#pragma unroll
    for (int i = ty; i < 32; i += 8)
        dst[(size_t)(c0 + i) * R + r0 + tx] = f2bf(tile[tx][i]);
}

// ---------------- GEMM (m97 structure): C[M][N] = A[M][K] * Bt[N][K]^T ----------------
// mode 0: Cout fp32.  mode 1: scatter epilogue -> Q[bh][t][d], K[bh][t][d], Vt[bh][d][t] (bf16)

__global__ __launch_bounds__(256) void gemm_bt_kernel(
    const u16* __restrict__ A, const u16* __restrict__ Bt,
    int M, int N, int K,
    float* __restrict__ Cout,
    u16* __restrict__ Qo, u16* __restrict__ Ko, u16* __restrict__ Vto,
    int mode)
{
    __shared__ u16 As[128 * 32];
    __shared__ u16 Bs[128 * 32];
    int t = threadIdx.x;
    int m0 = blockIdx.y * 128, n0 = blockIdx.x * 128;
    int lane = t & 63, w = t >> 6;
    int mw = (w >> 1) * 64, nw = (w & 1) * 64;
    int mr = lane & 15, quad = lane >> 4;

    f32x4 zero = {0.f, 0.f, 0.f, 0.f};
    f32x4 acc[4][4];
#pragma unroll
    for (int i = 0; i < 4; ++i)
#pragma unroll
        for (int j = 0; j < 4; ++j) acc[i][j] = zero;

    int rA = t >> 2, ko = (t & 3) << 3;
    const u16* gA0 = A + (size_t)(m0 + rA) * K + ko;
    const u16* gA1 = A + (size_t)(m0 + 64 + rA) * K + ko;
    const u16* gB0 = Bt + (size_t)(n0 + rA) * K + ko;
    const u16* gB1 = Bt + (size_t)(n0 + 64 + rA) * K + ko;
    u16* lA0 = As + (size_t)t * 8;
    u16* lA1 = As + (size_t)(256 + t) * 8;
    u16* lB0 = Bs + (size_t)t * 8;
    u16* lB1 = Bs + (size_t)(256 + t) * 8;

    for (int k0 = 0; k0 < K; k0 += 32) {
        async_copy16(gA0 + k0, lA0);
        async_copy16(gA1 + k0, lA1);
        async_copy16(gB0 + k0, lB0);
        async_copy16(gB1 + k0, lB1);
        __syncthreads();
        bf16x8 af[4], bfr[4];
#pragma unroll
        for (int i = 0; i < 4; ++i)
            af[i] = *(const bf16x8*)&As[(mw + i * 16 + mr) * 32 + quad * 8];
#pragma unroll
        for (int j = 0; j < 4; ++j)
            bfr[j] = *(const bf16x8*)&Bs[(nw + j * 16 + mr) * 32 + quad * 8];
#pragma unroll
        for (int i = 0; i < 4; ++i)
#pragma unroll
            for (int j = 0; j < 4; ++j)
                acc[i][j] = __builtin_amdgcn_mfma_f32_16x16x32_bf16(af[i], bfr[j], acc[i][j], 0, 0, 0);
        __syncthreads();
    }

    if (mode == 0) {
#pragma unroll
        for (int i = 0; i < 4; ++i)
#pragma unroll
            for (int j = 0; j < 4; ++j)
#pragma unroll
                for (int r = 0; r < 4; ++r) {
                    int rg = m0 + mw + i * 16 + quad * 4 + r;
                    int cg = n0 + nw + j * 16 + mr;
                    Cout[(size_t)rg * N + cg] = acc[i][j][r];
                }
    } else {
#pragma unroll
        for (int i = 0; i < 4; ++i)
#pragma unroll
            for (int j = 0; j < 4; ++j)
#pragma unroll
                for (int r = 0; r < 4; ++r) {
                    int rg = m0 + mw + i * 16 + quad * 4 + r;   // token
                    int cg = n0 + nw + j * 16 + mr;             // qkv column
                    float val = acc[i][j][r];
                    int part = cg >> 10, cc = cg & 1023;
                    int h = cc >> 6, d = cc & 63;
                    int b = rg >> 11, tt = rg & 2047;
                    int bh = b * NHH + h;
                    u16 bv = f2bf(val);
                    if (part == 0)
                        Qo[((size_t)bh * TT + tt) * HDD + d] = bv;
                    else if (part == 1)
                        Ko[((size_t)bh * TT + tt) * HDD + d] = bv;
                    else
                        Vto[((size_t)bh * HDD + d) * TT + tt] = bv;
                }
    }
}

// ---------------- flash attention: 1 wave per block, 16 q-rows, 32 kv per iter ----------------

__global__ __launch_bounds__(64) void attn_kernel(
    const u16* __restrict__ Q, const u16* __restrict__ Kt, const u16* __restrict__ Vt,
    u16* __restrict__ Y)
{
    __shared__ u16 Pl[16 * 40];   // stride 40 elems: 16B aligned b128 reads, low conflicts
    int lane = threadIdx.x;
    int m = lane & 15, quad = lane >> 4;
    int bid = blockIdx.x;
    int bh = bid >> 7;       // 128 q tiles per head
    int qt = bid & 127;
    int q0 = qt << 4;

    const u16* qbase = Q + ((size_t)bh * TT + q0 + m) * HDD + quad * 8;
    bf16x8 qf0 = *(const bf16x8*)(qbase);
    bf16x8 qf1 = *(const bf16x8*)(qbase + 32);
    const u16* kbase = Kt + (size_t)bh * TT * HDD;  // [t][d]
    const u16* vbase = Vt + (size_t)bh * HDD * TT;  // [d][t]

    float mi[4], li[4];
    f32x4 zero = {0.f, 0.f, 0.f, 0.f};
    f32x4 o[4];
#pragma unroll
    for (int r = 0; r < 4; ++r) { mi[r] = -1e30f; li[r] = 0.f; }
#pragma unroll
    for (int dg = 0; dg < 4; ++dg) o[dg] = zero;

    int last = (q0 + 15) >> 5;
    for (int ic = 0; ic <= last; ++ic) {
        int kv0 = ic << 5;
        const u16* kb = kbase + (size_t)(kv0 + m) * HDD + quad * 8;
        bf16x8 kf00 = *(const bf16x8*)(kb);
        bf16x8 kf01 = *(const bf16x8*)(kb + 32);
        bf16x8 kf10 = *(const bf16x8*)(kb + 16 * HDD);
        bf16x8 kf11 = *(const bf16x8*)(kb + 16 * HDD + 32);
        bf16x8 vf[4];
#pragma unroll
        for (int dg = 0; dg < 4; ++dg)
            vf[dg] = *(const bf16x8*)(vbase + (size_t)(dg * 16 + m) * TT + kv0 + quad * 8);

        f32x4 s0 = zero, s1 = zero;
        s0 = __builtin_amdgcn_mfma_f32_16x16x32_bf16(qf0, kf00, s0, 0, 0, 0);
        s0 = __builtin_amdgcn_mfma_f32_16x16x32_bf16(qf1, kf01, s0, 0, 0, 0);
        s1 = __builtin_amdgcn_mfma_f32_16x16x32_bf16(qf0, kf10, s1, 0, 0, 0);
        s1 = __builtin_amdgcn_mfma_f32_16x16x32_bf16(qf1, kf11, s1, 0, 0, 0);

        float p0[4], p1[4], lm[4];
        bool maskit = (ic == last);
#pragma unroll
        for (int r = 0; r < 4; ++r) {
            float a = s0[r] * 0.125f;
            float bv = s1[r] * 0.125f;
            if (maskit) {
                int row = q0 + quad * 4 + r;
                if (kv0 + m > row)      a  = -1e30f;
                if (kv0 + 16 + m > row) bv = -1e30f;
            }
            p0[r] = a; p1[r] = bv;
            lm[r] = fmaxf(a, bv);
        }
#pragma unroll
        for (int off = 1; off < 16; off <<= 1)
#pragma unroll
            for (int r = 0; r < 4; ++r)
                lm[r] = fmaxf(lm[r], __shfl_xor(lm[r], off, 64));

        float al[4], ls[4];
#pragma unroll
        for (int r = 0; r < 4; ++r) {
            float mn = fmaxf(mi[r], lm[r]);
            al[r] = __expf(mi[r] - mn);
            p0[r] = __expf(p0[r] - mn);
            p1[r] = __expf(p1[r] - mn);
            mi[r] = mn;
            ls[r] = p0[r] + p1[r];
        }
#pragma unroll
        for (int off = 1; off < 16; off <<= 1)
#pragma unroll
            for (int r = 0; r < 4; ++r)
                ls[r] += __shfl_xor(ls[r], off, 64);
#pragma unroll
        for (int r = 0; r < 4; ++r)
            li[r] = li[r] * al[r] + ls[r];
#pragma unroll
        for (int dg = 0; dg < 4; ++dg) {
            f32x4 tv = o[dg];
            tv[0] *= al[0]; tv[1] *= al[1]; tv[2] *= al[2]; tv[3] *= al[3];
            o[dg] = tv;
        }
        // P (C-layout) -> LDS -> A-layout
#pragma unroll
        for (int r = 0; r < 4; ++r) {
            Pl[(quad * 4 + r) * 40 + m]      = f2bf(p0[r]);
            Pl[(quad * 4 + r) * 40 + 16 + m] = f2bf(p1[r]);
        }
        __syncthreads();
        bf16x8 ap = *(const bf16x8*)&Pl[m * 40 + quad * 8];
#pragma unroll
        for (int dg = 0; dg < 4; ++dg)
            o[dg] = __builtin_amdgcn_mfma_f32_16x16x32_bf16(ap, vf[dg], o[dg], 0, 0, 0);
        __syncthreads();
    }

    int b = bh >> 4, h = bh & 15;
#pragma unroll
    for (int r = 0; r < 4; ++r) {
        float inv = 1.0f / li[r];
        int tt = q0 + quad * 4 + r;
        size_t rowoff = ((size_t)(b * TT + tt)) * CCH + h * HDD;
#pragma unroll
        for (int dg = 0; dg < 4; ++dg)
            Y[rowoff + dg * 16 + m] = f2bf(o[dg][r] * inv);
    }
}

// ---------------- launch ----------------

extern "C" void kernel_launch(void* const* d_in, const int* in_sizes, int n_in,
                              void* d_out, int out_size, void* d_ws, size_t ws_size,
                              hipStream_t stream) {
    const float* x      = (const float*)d_in[0];
    const float* w_attn = (const float*)d_in[1];
    const float* w_proj = (const float*)d_in[2];
    float* out = (float*)d_out;

    char* ws = (char*)d_ws;
    u16* x_bf   = (u16*)ws; ws += (size_t)M_TOK * CCH * 2;   // 8 MB
    u16* wqkvT  = (u16*)ws; ws += (size_t)N_QKV * CCH * 2;   // 6 MB
    u16* wprojT = (u16*)ws; ws += (size_t)CCH * CCH * 2;     // 2 MB
    u16* qb     = (u16*)ws; ws += (size_t)M_TOK * CCH * 2 / 4 * 1; // actually 32*2048*64*2 = 8 MB
    // note: Q is one third of qkv = 4096*1024 elems? No: 32 heads * 2048 t * 64 d = 4,194,304 elems = 8 MB
    ws = (char*)qb + (size_t)32 * TT * HDD * 2;
    u16* kb     = (u16*)ws; ws += (size_t)32 * TT * HDD * 2; // 8 MB
    u16* vtb    = (u16*)ws; ws += (size_t)32 * HDD * TT * 2; // 8 MB
    u16* yb     = (u16*)ws; ws += (size_t)M_TOK * CCH * 2;   // 8 MB

    // 1. cast x -> bf16
    cast_bf16_kernel<<<dim3(M_TOK * CCH / 4 / 256), dim3(256), 0, stream>>>(x, x_bf, M_TOK * CCH / 4);
    // 2. transpose weights -> bf16 [N][K]
    transpose_bf16_kernel<<<dim3(N_QKV / 32, CCH / 32), dim3(32, 8), 0, stream>>>(w_attn, wqkvT, CCH, N_QKV);
    transpose_bf16_kernel<<<dim3(CCH / 32, CCH / 32), dim3(32, 8), 0, stream>>>(w_proj, wprojT, CCH, CCH);
    // 3. QKV GEMM with scatter epilogue
    gemm_bt_kernel<<<dim3(N_QKV / 128, M_TOK / 128), dim3(256), 0, stream>>>(
        x_bf, wqkvT, M_TOK, N_QKV, CCH, nullptr, qb, kb, vtb, 1);
    // 4. flash attention
    attn_kernel<<<dim3(BB * NHH * (TT / 16)), dim3(64), 0, stream>>>(qb, kb, vtb, yb);
    // 5. output projection
    gemm_bt_kernel<<<dim3(CCH / 128, M_TOK / 128), dim3(256), 0, stream>>>(
        yb, wprojT, M_TOK, CCH, CCH, out, nullptr, nullptr, nullptr, 0);
}

// Round 2
// 302.501 us; speedup vs baseline: 1.2812x; 1.2812x over previous
//
#include <hip/hip_runtime.h>
#include <hip/hip_bf16.h>

#define BB 2
#define TT 2048
#define CCH 1024
#define NHH 16
#define HDD 64
#define M_TOK (BB*TT)      // 4096
#define N_QKV (3*CCH)      // 3072

typedef __attribute__((ext_vector_type(8))) short bf16x8;
typedef __attribute__((ext_vector_type(4))) float f32x4;
typedef unsigned short u16;
typedef unsigned int u32;

__device__ __forceinline__ u16 f2bf(float f) {
    union { float f; u32 u; } v; v.f = f;
    u32 u = v.u;
    u32 r = (u + 0x7FFFu + ((u >> 16) & 1u)) >> 16;
    return (u16)r;
}

__device__ __forceinline__ void async_copy16(const void* g, void* l) {
    __builtin_amdgcn_global_load_lds((__attribute__((address_space(1))) void*)g,
                                     (__attribute__((address_space(3))) void*)l,
                                     16, 0, 0);
}

// ---------------- pre-pass kernels ----------------

__global__ __launch_bounds__(256) void cast_bf16_kernel(
    const float* __restrict__ src, u16* __restrict__ dst, int n4) {
    int i = blockIdx.x * 256 + threadIdx.x;
    if (i < n4) {
        float4 f = ((const float4*)src)[i];
        ushort4 o;
        o.x = f2bf(f.x); o.y = f2bf(f.y); o.z = f2bf(f.z); o.w = f2bf(f.w);
        ((ushort4*)dst)[i] = o;
    }
}

// src [R][Cn] fp32 -> dst [Cn][R] bf16
__global__ __launch_bounds__(256) void transpose_bf16_kernel(
    const float* __restrict__ src, u16* __restrict__ dst, int R, int Cn) {
    __shared__ float tile[32][33];
    int c0 = blockIdx.x * 32, r0 = blockIdx.y * 32;
    int tx = threadIdx.x, ty = threadIdx.y;
#pragma unroll
    for (int i = ty; i < 32; i += 8)
        tile[i][tx] = src[(size_t)(r0 + i) * Cn + c0 + tx];
    __syncthreads();
#pragma unroll
    for (int i = ty; i < 32; i += 8)
        dst[(size_t)(c0 + i) * R + r0 + tx] = f2bf(tile[tx][i]);
}

// ---------------- GEMM (m97 structure): C[M][N] = A[M][K] * Bt[N][K]^T ----------------
// mode 0: Cout fp32.  mode 1: scatter epilogue -> Q[bh][t][d], K[bh][t][d], Vt[bh][d][t] (bf16)

__global__ __launch_bounds__(256) void gemm_bt_kernel(
    const u16* __restrict__ A, const u16* __restrict__ Bt,
    int M, int N, int K,
    float* __restrict__ Cout,
    u16* __restrict__ Qo, u16* __restrict__ Ko, u16* __restrict__ Vto,
    int mode)
{
    __shared__ u16 As[128 * 32];
    __shared__ u16 Bs[128 * 32];
    int t = threadIdx.x;
    int m0 = blockIdx.y * 128, n0 = blockIdx.x * 128;
    int lane = t & 63, w = t >> 6;
    int mw = (w >> 1) * 64, nw = (w & 1) * 64;
    int mr = lane & 15, quad = lane >> 4;

    f32x4 zero = {0.f, 0.f, 0.f, 0.f};
    f32x4 acc[4][4];
#pragma unroll
    for (int i = 0; i < 4; ++i)
#pragma unroll
        for (int j = 0; j < 4; ++j) acc[i][j] = zero;

    int rA = t >> 2, ko = (t & 3) << 3;
    const u16* gA0 = A + (size_t)(m0 + rA) * K + ko;
    const u16* gA1 = A + (size_t)(m0 + 64 + rA) * K + ko;
    const u16* gB0 = Bt + (size_t)(n0 + rA) * K + ko;
    const u16* gB1 = Bt + (size_t)(n0 + 64 + rA) * K + ko;
    u16* lA0 = As + (size_t)t * 8;
    u16* lA1 = As + (size_t)(256 + t) * 8;
    u16* lB0 = Bs + (size_t)t * 8;
    u16* lB1 = Bs + (size_t)(256 + t) * 8;

    for (int k0 = 0; k0 < K; k0 += 32) {
        async_copy16(gA0 + k0, lA0);
        async_copy16(gA1 + k0, lA1);
        async_copy16(gB0 + k0, lB0);
        async_copy16(gB1 + k0, lB1);
        __syncthreads();
        bf16x8 af[4], bfr[4];
#pragma unroll
        for (int i = 0; i < 4; ++i)
            af[i] = *(const bf16x8*)&As[(mw + i * 16 + mr) * 32 + quad * 8];
#pragma unroll
        for (int j = 0; j < 4; ++j)
            bfr[j] = *(const bf16x8*)&Bs[(nw + j * 16 + mr) * 32 + quad * 8];
#pragma unroll
        for (int i = 0; i < 4; ++i)
#pragma unroll
            for (int j = 0; j < 4; ++j)
                acc[i][j] = __builtin_amdgcn_mfma_f32_16x16x32_bf16(af[i], bfr[j], acc[i][j], 0, 0, 0);
        __syncthreads();
    }

    if (mode == 0) {
#pragma unroll
        for (int i = 0; i < 4; ++i)
#pragma unroll
            for (int j = 0; j < 4; ++j)
#pragma unroll
                for (int r = 0; r < 4; ++r) {
                    int rg = m0 + mw + i * 16 + quad * 4 + r;
                    int cg = n0 + nw + j * 16 + mr;
                    Cout[(size_t)rg * N + cg] = acc[i][j][r];
                }
    } else {
#pragma unroll
        for (int i = 0; i < 4; ++i)
#pragma unroll
            for (int j = 0; j < 4; ++j)
#pragma unroll
                for (int r = 0; r < 4; ++r) {
                    int rg = m0 + mw + i * 16 + quad * 4 + r;   // token
                    int cg = n0 + nw + j * 16 + mr;             // qkv column
                    float val = acc[i][j][r];
                    int part = cg >> 10, cc = cg & 1023;
                    int h = cc >> 6, d = cc & 63;
                    int b = rg >> 11, tt = rg & 2047;
                    int bh = b * NHH + h;
                    u16 bv = f2bf(val);
                    if (part == 0)
                        Qo[((size_t)bh * TT + tt) * HDD + d] = bv;
                    else if (part == 1)
                        Ko[((size_t)bh * TT + tt) * HDD + d] = bv;
                    else
                        Vto[((size_t)bh * HDD + d) * TT + tt] = bv;
                }
    }
}

// ---------------- flash attention v2 ----------------
// S^T orientation: softmax reduce = in-lane over regs + 2 shuffles.
// 4 waves/block (independent q-tiles of 16 rows), KV chunk 64/iter,
// wave-private P LDS (stride 80), NO barriers in inner loop.

#define PSTRIDE 80

__global__ __launch_bounds__(256) void attn_kernel(
    const u16* __restrict__ Q, const u16* __restrict__ Kt, const u16* __restrict__ Vt,
    u16* __restrict__ Y)
{
    __shared__ u16 Pl[4][16 * PSTRIDE];
    int t = threadIdx.x;
    int w = t >> 6, lane = t & 63;
    int m = lane & 15, quad = lane >> 4;

    int bid = blockIdx.x;
    int bh = bid & 31;                 // 32 head-batches
    int qblk = 31 - (bid >> 5);        // heavy q-tiles dispatched first
    int qt = qblk * 4 + w;             // 0..127
    int q0 = qt << 4;

    const u16* qbase = Q + ((size_t)bh * TT + q0 + m) * HDD + quad * 8;
    bf16x8 qf0 = *(const bf16x8*)(qbase);
    bf16x8 qf1 = *(const bf16x8*)(qbase + 32);
    const u16* kbase = Kt + (size_t)bh * TT * HDD;  // [t][d]
    const u16* vbase = Vt + (size_t)bh * HDD * TT;  // [d][t]
    u16* pb = &Pl[w][0];

    float mi = -1e30f, li = 0.f;
    f32x4 zero = {0.f, 0.f, 0.f, 0.f};
    f32x4 o[4];
#pragma unroll
    for (int dg = 0; dg < 4; ++dg) o[dg] = zero;

    int qcol = q0 + m;
    int last = (q0 + 15) >> 6;
    for (int ic = 0; ic <= last; ++ic) {
        int kv0 = ic << 6;
        // ---- QK^T -> S^T tiles: C[kv_local][q], kv on quad*4+r, q on lane&15
        f32x4 st[4];
#pragma unroll
        for (int kc = 0; kc < 4; ++kc) {
            const u16* kb = kbase + (size_t)(kv0 + kc * 16 + m) * HDD + quad * 8;
            bf16x8 kf0 = *(const bf16x8*)(kb);
            bf16x8 kf1 = *(const bf16x8*)(kb + 32);
            f32x4 s = __builtin_amdgcn_mfma_f32_16x16x32_bf16(kf0, qf0, zero, 0, 0, 0);
            st[kc]   = __builtin_amdgcn_mfma_f32_16x16x32_bf16(kf1, qf1, s, 0, 0, 0);
        }
        // ---- V^T fragments (A-layout: d on lane&15, kv on quad*8+j) — issue early
        bf16x8 vf[4][2];
#pragma unroll
        for (int dg = 0; dg < 4; ++dg) {
            const u16* vb = vbase + (size_t)(dg * 16 + m) * TT + kv0 + quad * 8;
            vf[dg][0] = *(const bf16x8*)(vb);
            vf[dg][1] = *(const bf16x8*)(vb + 32);
        }
        // ---- scale + causal mask
        float p[16];
        bool maskit = (ic == last);
#pragma unroll
        for (int kc = 0; kc < 4; ++kc)
#pragma unroll
            for (int r = 0; r < 4; ++r) {
                float v = st[kc][r] * 0.125f;
                if (maskit && (kv0 + kc * 16 + quad * 4 + r > qcol)) v = -1e30f;
                p[kc * 4 + r] = v;
            }
        // ---- online softmax (per q-column = per lane group of 4)
        float lm = p[0];
#pragma unroll
        for (int i = 1; i < 16; ++i) lm = fmaxf(lm, p[i]);
        lm = fmaxf(lm, __shfl_xor(lm, 16, 64));
        lm = fmaxf(lm, __shfl_xor(lm, 32, 64));
        float mn = fmaxf(mi, lm);
        float al = __expf(mi - mn);
        float ls = 0.f;
#pragma unroll
        for (int i = 0; i < 16; ++i) { p[i] = __expf(p[i] - mn); ls += p[i]; }
        ls += __shfl_xor(ls, 16, 64);
        ls += __shfl_xor(ls, 32, 64);
        li = li * al + ls;
        mi = mn;
#pragma unroll
        for (int dg = 0; dg < 4; ++dg) {
            f32x4 tv = o[dg];
            tv[0] *= al; tv[1] *= al; tv[2] *= al; tv[3] *= al;
            o[dg] = tv;
        }
        // ---- P^T -> wave-private LDS, stored [q][kv] (stride 80)
#pragma unroll
        for (int kc = 0; kc < 4; ++kc) {
            u32 lo = (u32)f2bf(p[kc * 4 + 0]) | ((u32)f2bf(p[kc * 4 + 1]) << 16);
            u32 hi = (u32)f2bf(p[kc * 4 + 2]) | ((u32)f2bf(p[kc * 4 + 3]) << 16);
            uint2 pk; pk.x = lo; pk.y = hi;
            *(uint2*)&pb[m * PSTRIDE + kc * 16 + quad * 4] = pk;
        }
        // ---- PV: O^T[d][q] += V^T-frag x P^T-frag (B-layout: q on lane&15, kv on quad*8+j)
#pragma unroll
        for (int ks = 0; ks < 2; ++ks) {
            bf16x8 pf = *(const bf16x8*)&pb[m * PSTRIDE + ks * 32 + quad * 8];
#pragma unroll
            for (int dg = 0; dg < 4; ++dg)
                o[dg] = __builtin_amdgcn_mfma_f32_16x16x32_bf16(vf[dg][ks], pf, o[dg], 0, 0, 0);
        }
    }
    // ---- epilogue: O^T tile dg: rows d=dg*16+quad*4+r, col q=m
    float inv = 1.0f / li;
    int b = bh >> 4, h = bh & 15;
    int tt = q0 + m;
    size_t rowoff = ((size_t)(b * TT + tt)) * CCH + h * HDD;
#pragma unroll
    for (int dg = 0; dg < 4; ++dg) {
        ushort4 ov;
        ov.x = f2bf(o[dg][0] * inv);
        ov.y = f2bf(o[dg][1] * inv);
        ov.z = f2bf(o[dg][2] * inv);
        ov.w = f2bf(o[dg][3] * inv);
        *(ushort4*)&Y[rowoff + dg * 16 + quad * 4] = ov;
    }
}

// ---------------- launch ----------------

extern "C" void kernel_launch(void* const* d_in, const int* in_sizes, int n_in,
                              void* d_out, int out_size, void* d_ws, size_t ws_size,
                              hipStream_t stream) {
    const float* x      = (const float*)d_in[0];
    const float* w_attn = (const float*)d_in[1];
    const float* w_proj = (const float*)d_in[2];
    float* out = (float*)d_out;

    char* ws = (char*)d_ws;
    u16* x_bf   = (u16*)ws; ws += (size_t)M_TOK * CCH * 2;        // 8 MB
    u16* wqkvT  = (u16*)ws; ws += (size_t)N_QKV * CCH * 2;        // 6 MB
    u16* wprojT = (u16*)ws; ws += (size_t)CCH * CCH * 2;          // 2 MB
    u16* qb     = (u16*)ws; ws += (size_t)BB * NHH * TT * HDD * 2; // 8 MB
    u16* kb     = (u16*)ws; ws += (size_t)BB * NHH * TT * HDD * 2; // 8 MB
    u16* vtb    = (u16*)ws; ws += (size_t)BB * NHH * HDD * TT * 2; // 8 MB
    u16* yb     = (u16*)ws; ws += (size_t)M_TOK * CCH * 2;        // 8 MB

    // 1. cast x -> bf16
    cast_bf16_kernel<<<dim3(M_TOK * CCH / 4 / 256), dim3(256), 0, stream>>>(x, x_bf, M_TOK * CCH / 4);
    // 2. transpose weights -> bf16 [N][K]
    transpose_bf16_kernel<<<dim3(N_QKV / 32, CCH / 32), dim3(32, 8), 0, stream>>>(w_attn, wqkvT, CCH, N_QKV);
    transpose_bf16_kernel<<<dim3(CCH / 32, CCH / 32), dim3(32, 8), 0, stream>>>(w_proj, wprojT, CCH, CCH);
    // 3. QKV GEMM with scatter epilogue
    gemm_bt_kernel<<<dim3(N_QKV / 128, M_TOK / 128), dim3(256), 0, stream>>>(
        x_bf, wqkvT, M_TOK, N_QKV, CCH, nullptr, qb, kb, vtb, 1);
    // 4. flash attention (S^T orientation, 4 waves/block, no inner barriers)
    attn_kernel<<<dim3(32 * 32), dim3(256), 0, stream>>>(qb, kb, vtb, yb);
    // 5. output projection
    gemm_bt_kernel<<<dim3(CCH / 128, M_TOK / 128), dim3(256), 0, stream>>>(
        yb, wprojT, M_TOK, CCH, CCH, out, nullptr, nullptr, nullptr, 0);
}

// Round 3
// 285.181 us; speedup vs baseline: 1.3590x; 1.0607x over previous
//
#include <hip/hip_runtime.h>
#include <hip/hip_bf16.h>

#define BB 2
#define TT 2048
#define CCH 1024
#define NHH 16
#define HDD 64
#define M_TOK (BB*TT)      // 4096
#define N_QKV (3*CCH)      // 3072

typedef __attribute__((ext_vector_type(8))) short bf16x8;
typedef __attribute__((ext_vector_type(4))) float f32x4;
typedef unsigned short u16;
typedef unsigned int u32;

__device__ __forceinline__ u16 f2bf(float f) {
    union { float f; u32 u; } v; v.f = f;
    u32 u = v.u;
    u32 r = (u + 0x7FFFu + ((u >> 16) & 1u)) >> 16;
    return (u16)r;
}

// pack hi16(a),hi16(b) -> u32 {b.hi<<16 | a.hi} with +0x8000 rounding
__device__ __forceinline__ u32 pk_bf16(float a, float b) {
    u32 ua = __float_as_uint(a) + 0x8000u;
    u32 ub = __float_as_uint(b) + 0x8000u;
    return __builtin_amdgcn_perm(ub, ua, 0x07060302u);
}

__device__ __forceinline__ void async_copy16(const void* g, void* l) {
    __builtin_amdgcn_global_load_lds((__attribute__((address_space(1))) void*)g,
                                     (__attribute__((address_space(3))) void*)l,
                                     16, 0, 0);
}

// ---------------- pre-pass kernels ----------------

__global__ __launch_bounds__(256) void cast_bf16_kernel(
    const float* __restrict__ src, u16* __restrict__ dst, int n4) {
    int i = blockIdx.x * 256 + threadIdx.x;
    if (i < n4) {
        float4 f = ((const float4*)src)[i];
        ushort4 o;
        o.x = f2bf(f.x); o.y = f2bf(f.y); o.z = f2bf(f.z); o.w = f2bf(f.w);
        ((ushort4*)dst)[i] = o;
    }
}

// src [R][Cn] fp32 -> dst [Cn][R] bf16
__global__ __launch_bounds__(256) void transpose_bf16_kernel(
    const float* __restrict__ src, u16* __restrict__ dst, int R, int Cn) {
    __shared__ float tile[32][33];
    int c0 = blockIdx.x * 32, r0 = blockIdx.y * 32;
    int tx = threadIdx.x, ty = threadIdx.y;
#pragma unroll
    for (int i = ty; i < 32; i += 8)
        tile[i][tx] = src[(size_t)(r0 + i) * Cn + c0 + tx];
    __syncthreads();
#pragma unroll
    for (int i = ty; i < 32; i += 8)
        dst[(size_t)(c0 + i) * R + r0 + tx] = f2bf(tile[tx][i]);
}

// ---------------- GEMM (m97 structure): C[M][N] = A[M][K] * Bt[N][K]^T ----------------

__global__ __launch_bounds__(256) void gemm_bt_kernel(
    const u16* __restrict__ A, const u16* __restrict__ Bt,
    int M, int N, int K,
    float* __restrict__ Cout,
    u16* __restrict__ Qo, u16* __restrict__ Ko, u16* __restrict__ Vto,
    int mode)
{
    __shared__ u16 As[128 * 32];
    __shared__ u16 Bs[128 * 32];
    int t = threadIdx.x;
    int m0 = blockIdx.y * 128, n0 = blockIdx.x * 128;
    int lane = t & 63, w = t >> 6;
    int mw = (w >> 1) * 64, nw = (w & 1) * 64;
    int mr = lane & 15, quad = lane >> 4;

    f32x4 zero = {0.f, 0.f, 0.f, 0.f};
    f32x4 acc[4][4];
#pragma unroll
    for (int i = 0; i < 4; ++i)
#pragma unroll
        for (int j = 0; j < 4; ++j) acc[i][j] = zero;

    int rA = t >> 2, ko = (t & 3) << 3;
    const u16* gA0 = A + (size_t)(m0 + rA) * K + ko;
    const u16* gA1 = A + (size_t)(m0 + 64 + rA) * K + ko;
    const u16* gB0 = Bt + (size_t)(n0 + rA) * K + ko;
    const u16* gB1 = Bt + (size_t)(n0 + 64 + rA) * K + ko;
    u16* lA0 = As + (size_t)t * 8;
    u16* lA1 = As + (size_t)(256 + t) * 8;
    u16* lB0 = Bs + (size_t)t * 8;
    u16* lB1 = Bs + (size_t)(256 + t) * 8;

    for (int k0 = 0; k0 < K; k0 += 32) {
        async_copy16(gA0 + k0, lA0);
        async_copy16(gA1 + k0, lA1);
        async_copy16(gB0 + k0, lB0);
        async_copy16(gB1 + k0, lB1);
        __syncthreads();
        bf16x8 af[4], bfr[4];
#pragma unroll
        for (int i = 0; i < 4; ++i)
            af[i] = *(const bf16x8*)&As[(mw + i * 16 + mr) * 32 + quad * 8];
#pragma unroll
        for (int j = 0; j < 4; ++j)
            bfr[j] = *(const bf16x8*)&Bs[(nw + j * 16 + mr) * 32 + quad * 8];
#pragma unroll
        for (int i = 0; i < 4; ++i)
#pragma unroll
            for (int j = 0; j < 4; ++j)
                acc[i][j] = __builtin_amdgcn_mfma_f32_16x16x32_bf16(af[i], bfr[j], acc[i][j], 0, 0, 0);
        __syncthreads();
    }

    if (mode == 0) {
#pragma unroll
        for (int i = 0; i < 4; ++i)
#pragma unroll
            for (int j = 0; j < 4; ++j)
#pragma unroll
                for (int r = 0; r < 4; ++r) {
                    int rg = m0 + mw + i * 16 + quad * 4 + r;
                    int cg = n0 + nw + j * 16 + mr;
                    Cout[(size_t)rg * N + cg] = acc[i][j][r];
                }
    } else {
#pragma unroll
        for (int i = 0; i < 4; ++i)
#pragma unroll
            for (int j = 0; j < 4; ++j)
#pragma unroll
                for (int r = 0; r < 4; ++r) {
                    int rg = m0 + mw + i * 16 + quad * 4 + r;   // token
                    int cg = n0 + nw + j * 16 + mr;             // qkv column
                    float val = acc[i][j][r];
                    int part = cg >> 10, cc = cg & 1023;
                    int h = cc >> 6, d = cc & 63;
                    int b = rg >> 11, tt = rg & 2047;
                    int bh = b * NHH + h;
                    u16 bv = f2bf(val);
                    if (part == 0)
                        Qo[((size_t)bh * TT + tt) * HDD + d] = bv;
                    else if (part == 1)
                        Ko[((size_t)bh * TT + tt) * HDD + d] = bv;
                    else
                        Vto[((size_t)bh * HDD + d) * TT + tt] = bv;
                }
    }
}

// ---------------- flash attention v3 ----------------
// S^T orientation, 2 waves/block, XCD-pinned heads (4 heads per XCD => KV fits L2),
// masked iteration split out, exp2-native softmax, perm-packed bf16, stride-72 P LDS.

#define PSTRIDE 72

template<bool MASK>
__device__ __forceinline__ void attn_iter(
    int kv0, const u16* __restrict__ kbase, const u16* __restrict__ vbase,
    u16* __restrict__ pb, bf16x8 qf0, bf16x8 qf1,
    int m, int quad, int qcol, f32x4 (&o)[4], float& mi, float& li)
{
    f32x4 zero = {0.f, 0.f, 0.f, 0.f};
    const float SC = 0.125f * 1.44269504f;   // scale * log2(e)
    // QK^T -> S^T: kv on quad*4+r, q on lane&15
    f32x4 st[4];
#pragma unroll
    for (int kc = 0; kc < 4; ++kc) {
        const u16* kb = kbase + (size_t)(kv0 + kc * 16 + m) * HDD + quad * 8;
        bf16x8 kf0 = *(const bf16x8*)(kb);
        bf16x8 kf1 = *(const bf16x8*)(kb + 32);
        f32x4 s = __builtin_amdgcn_mfma_f32_16x16x32_bf16(kf0, qf0, zero, 0, 0, 0);
        st[kc]   = __builtin_amdgcn_mfma_f32_16x16x32_bf16(kf1, qf1, s, 0, 0, 0);
    }
    // V^T fragments (A-layout), prefetch during softmax
    bf16x8 vf[4][2];
#pragma unroll
    for (int dg = 0; dg < 4; ++dg) {
        const u16* vb = vbase + (size_t)(dg * 16 + m) * TT + kv0 + quad * 8;
        vf[dg][0] = *(const bf16x8*)(vb);
        vf[dg][1] = *(const bf16x8*)(vb + 32);
    }
    float p[16];
#pragma unroll
    for (int kc = 0; kc < 4; ++kc)
#pragma unroll
        for (int r = 0; r < 4; ++r) {
            float v = st[kc][r] * SC;
            if (MASK && (kv0 + kc * 16 + quad * 4 + r > qcol)) v = -1e30f;
            p[kc * 4 + r] = v;
        }
    float lm = fmaxf(fmaxf(fmaxf(p[0], p[1]), fmaxf(p[2], p[3])),
                     fmaxf(fmaxf(p[4], p[5]), fmaxf(p[6], p[7])));
    float lm2 = fmaxf(fmaxf(fmaxf(p[8], p[9]), fmaxf(p[10], p[11])),
                      fmaxf(fmaxf(p[12], p[13]), fmaxf(p[14], p[15])));
    lm = fmaxf(lm, lm2);
    lm = fmaxf(lm, __shfl_xor(lm, 16, 64));
    lm = fmaxf(lm, __shfl_xor(lm, 32, 64));
    float mn = fmaxf(mi, lm);
    float al = __builtin_amdgcn_exp2f(mi - mn);
    float ls = 0.f;
#pragma unroll
    for (int i = 0; i < 16; ++i) { p[i] = __builtin_amdgcn_exp2f(p[i] - mn); ls += p[i]; }
    ls += __shfl_xor(ls, 16, 64);
    ls += __shfl_xor(ls, 32, 64);
    li = li * al + ls;
    mi = mn;
#pragma unroll
    for (int dg = 0; dg < 4; ++dg) {
        f32x4 tv = o[dg];
        tv[0] *= al; tv[1] *= al; tv[2] *= al; tv[3] *= al;
        o[dg] = tv;
    }
    // P^T -> wave-private LDS [q][kv], stride 72 (2-way bank alias = free)
#pragma unroll
    for (int kc = 0; kc < 4; ++kc) {
        uint2 pk;
        pk.x = pk_bf16(p[kc * 4 + 0], p[kc * 4 + 1]);
        pk.y = pk_bf16(p[kc * 4 + 2], p[kc * 4 + 3]);
        *(uint2*)&pb[m * PSTRIDE + kc * 16 + quad * 4] = pk;
    }
    // PV: O^T += V^T-frag x P^T-frag
#pragma unroll
    for (int ks = 0; ks < 2; ++ks) {
        bf16x8 pf = *(const bf16x8*)&pb[m * PSTRIDE + ks * 32 + quad * 8];
#pragma unroll
        for (int dg = 0; dg < 4; ++dg)
            o[dg] = __builtin_amdgcn_mfma_f32_16x16x32_bf16(vf[dg][ks], pf, o[dg], 0, 0, 0);
    }
}

__global__ __launch_bounds__(128) void attn_kernel(
    const u16* __restrict__ Q, const u16* __restrict__ Kt, const u16* __restrict__ Vt,
    u16* __restrict__ Y)
{
    __shared__ u16 Pl[2][16 * PSTRIDE];
    int t = threadIdx.x;
    int w = t >> 6, lane = t & 63;
    int m = lane & 15, quad = lane >> 4;

    // XCD-pinned mapping: bid&7 = xcd hosts heads {xcd, xcd+8, xcd+16, xcd+24}
    int bid = blockIdx.x;
    int xcd = bid & 7;
    int c   = bid >> 3;              // 0..255
    int qt  = 127 - (c >> 1);        // heavy first
    int g   = (c & 1) * 2 + w;       // head-in-group 0..3
    int bh  = xcd + 8 * g;
    int q0 = qt << 4;

    const u16* qbase = Q + ((size_t)bh * TT + q0 + m) * HDD + quad * 8;
    bf16x8 qf0 = *(const bf16x8*)(qbase);
    bf16x8 qf1 = *(const bf16x8*)(qbase + 32);
    const u16* kbase = Kt + (size_t)bh * TT * HDD;  // [t][d]
    const u16* vbase = Vt + (size_t)bh * HDD * TT;  // [d][t]
    u16* pb = &Pl[w][0];

    float mi = -1e30f, li = 0.f;
    f32x4 zero = {0.f, 0.f, 0.f, 0.f};
    f32x4 o[4];
#pragma unroll
    for (int dg = 0; dg < 4; ++dg) o[dg] = zero;

    int qcol = q0 + m;
    int last = (q0 + 15) >> 6;
    for (int ic = 0; ic < last; ++ic)
        attn_iter<false>(ic << 6, kbase, vbase, pb, qf0, qf1, m, quad, qcol, o, mi, li);
    attn_iter<true>(last << 6, kbase, vbase, pb, qf0, qf1, m, quad, qcol, o, mi, li);

    // epilogue: O^T tile dg: rows d=dg*16+quad*4+r, col q=m
    float inv = 1.0f / li;
    int b = bh >> 4, h = bh & 15;
    int tt = q0 + m;
    size_t rowoff = ((size_t)(b * TT + tt)) * CCH + h * HDD;
#pragma unroll
    for (int dg = 0; dg < 4; ++dg) {
        uint2 ov;
        ov.x = pk_bf16(o[dg][0] * inv, o[dg][1] * inv);
        ov.y = pk_bf16(o[dg][2] * inv, o[dg][3] * inv);
        *(uint2*)&Y[rowoff + dg * 16 + quad * 4] = ov;
    }
}

// ---------------- launch ----------------

extern "C" void kernel_launch(void* const* d_in, const int* in_sizes, int n_in,
                              void* d_out, int out_size, void* d_ws, size_t ws_size,
                              hipStream_t stream) {
    const float* x      = (const float*)d_in[0];
    const float* w_attn = (const float*)d_in[1];
    const float* w_proj = (const float*)d_in[2];
    float* out = (float*)d_out;

    char* ws = (char*)d_ws;
    u16* x_bf   = (u16*)ws; ws += (size_t)M_TOK * CCH * 2;         // 8 MB
    u16* wqkvT  = (u16*)ws; ws += (size_t)N_QKV * CCH * 2;         // 6 MB
    u16* wprojT = (u16*)ws; ws += (size_t)CCH * CCH * 2;           // 2 MB
    u16* qb     = (u16*)ws; ws += (size_t)BB * NHH * TT * HDD * 2; // 8 MB
    u16* kb     = (u16*)ws; ws += (size_t)BB * NHH * TT * HDD * 2; // 8 MB
    u16* vtb    = (u16*)ws; ws += (size_t)BB * NHH * HDD * TT * 2; // 8 MB
    u16* yb     = (u16*)ws; ws += (size_t)M_TOK * CCH * 2;         // 8 MB

    // 1. cast x -> bf16
    cast_bf16_kernel<<<dim3(M_TOK * CCH / 4 / 256), dim3(256), 0, stream>>>(x, x_bf, M_TOK * CCH / 4);
    // 2. transpose weights -> bf16 [N][K]
    transpose_bf16_kernel<<<dim3(N_QKV / 32, CCH / 32), dim3(32, 8), 0, stream>>>(w_attn, wqkvT, CCH, N_QKV);
    transpose_bf16_kernel<<<dim3(CCH / 32, CCH / 32), dim3(32, 8), 0, stream>>>(w_proj, wprojT, CCH, CCH);
    // 3. QKV GEMM with scatter epilogue
    gemm_bt_kernel<<<dim3(N_QKV / 128, M_TOK / 128), dim3(256), 0, stream>>>(
        x_bf, wqkvT, M_TOK, N_QKV, CCH, nullptr, qb, kb, vtb, 1);
    // 4. flash attention (2 waves/block, XCD-pinned heads)
    attn_kernel<<<dim3(2048), dim3(128), 0, stream>>>(qb, kb, vtb, yb);
    // 5. output projection
    gemm_bt_kernel<<<dim3(CCH / 128, M_TOK / 128), dim3(256), 0, stream>>>(
        yb, wprojT, M_TOK, CCH, CCH, out, nullptr, nullptr, nullptr, 0);
}

// Round 4
// 200.268 us; speedup vs baseline: 1.9352x; 1.4240x over previous
//
#include <hip/hip_runtime.h>
#include <hip/hip_bf16.h>

#define BB 2
#define TT 2048
#define CCH 1024
#define NHH 16
#define HDD 64
#define M_TOK (BB*TT)      // 4096
#define N_QKV (3*CCH)      // 3072

typedef __attribute__((ext_vector_type(8))) short bf16x8;
typedef __attribute__((ext_vector_type(4))) float f32x4;
typedef unsigned short u16;
typedef unsigned int u32;

__device__ __forceinline__ u16 f2bf(float f) {
    union { float f; u32 u; } v; v.f = f;
    u32 u = v.u;
    u32 r = (u + 0x7FFFu + ((u >> 16) & 1u)) >> 16;
    return (u16)r;
}

// pack hi16(a),hi16(b) -> u32 {b.hi<<16 | a.hi} with +0x8000 rounding
__device__ __forceinline__ u32 pk_bf16(float a, float b) {
    u32 ua = __float_as_uint(a) + 0x8000u;
    u32 ub = __float_as_uint(b) + 0x8000u;
    return __builtin_amdgcn_perm(ub, ua, 0x07060302u);
}

__device__ __forceinline__ void async_copy16(const void* g, void* l) {
    __builtin_amdgcn_global_load_lds((__attribute__((address_space(1))) void*)g,
                                     (__attribute__((address_space(3))) void*)l,
                                     16, 0, 0);
}

// ---------------- pre-pass kernels ----------------

__global__ __launch_bounds__(256) void cast_bf16_kernel(
    const float* __restrict__ src, u16* __restrict__ dst, int n4) {
    int i = blockIdx.x * 256 + threadIdx.x;
    if (i < n4) {
        float4 f = ((const float4*)src)[i];
        ushort4 o;
        o.x = f2bf(f.x); o.y = f2bf(f.y); o.z = f2bf(f.z); o.w = f2bf(f.w);
        ((ushort4*)dst)[i] = o;
    }
}

// src [R][Cn] fp32 -> dst [Cn][R] bf16
__global__ __launch_bounds__(256) void transpose_bf16_kernel(
    const float* __restrict__ src, u16* __restrict__ dst, int R, int Cn) {
    __shared__ float tile[32][33];
    int c0 = blockIdx.x * 32, r0 = blockIdx.y * 32;
    int tx = threadIdx.x, ty = threadIdx.y;
#pragma unroll
    for (int i = ty; i < 32; i += 8)
        tile[i][tx] = src[(size_t)(r0 + i) * Cn + c0 + tx];
    __syncthreads();
#pragma unroll
    for (int i = ty; i < 32; i += 8)
        dst[(size_t)(c0 + i) * R + r0 + tx] = f2bf(tile[tx][i]);
}

// V [bh][t][d] bf16 -> Vt [bh][d][t] bf16
__global__ __launch_bounds__(256) void transpose_v_kernel(
    const u16* __restrict__ src, u16* __restrict__ dst) {
    __shared__ u16 tile[32][34];
    int t0 = blockIdx.x * 32, d0 = blockIdx.y * 32, bh = blockIdx.z;
    int tx = threadIdx.x, ty = threadIdx.y;
    const u16* s = src + (size_t)bh * TT * HDD;
    u16* d = dst + (size_t)bh * HDD * TT;
#pragma unroll
    for (int i = ty; i < 32; i += 8)
        tile[i][tx] = s[(size_t)(t0 + i) * HDD + d0 + tx];
    __syncthreads();
#pragma unroll
    for (int i = ty; i < 32; i += 8)
        d[(size_t)(d0 + i) * TT + t0 + tx] = tile[tx][i];
}

// ---------------- GEMM (m97 structure): C[M][N] = A[M][K] * Bt[N][K]^T ----------------
// mode 0: Cout fp32.  mode 1: epilogue -> Q/K/V [bh][t][d] bf16 rows (coalesced)

__global__ __launch_bounds__(256) void gemm_bt_kernel(
    const u16* __restrict__ A, const u16* __restrict__ Bt,
    int M, int N, int K,
    float* __restrict__ Cout,
    u16* __restrict__ Qo, u16* __restrict__ Ko, u16* __restrict__ Vo,
    int mode)
{
    __shared__ u16 As[128 * 32];
    __shared__ u16 Bs[128 * 32];
    int t = threadIdx.x;
    int m0 = blockIdx.y * 128, n0 = blockIdx.x * 128;
    int lane = t & 63, w = t >> 6;
    int mw = (w >> 1) * 64, nw = (w & 1) * 64;
    int mr = lane & 15, quad = lane >> 4;

    f32x4 zero = {0.f, 0.f, 0.f, 0.f};
    f32x4 acc[4][4];
#pragma unroll
    for (int i = 0; i < 4; ++i)
#pragma unroll
        for (int j = 0; j < 4; ++j) acc[i][j] = zero;

    int rA = t >> 2, ko = (t & 3) << 3;
    const u16* gA0 = A + (size_t)(m0 + rA) * K + ko;
    const u16* gA1 = A + (size_t)(m0 + 64 + rA) * K + ko;
    const u16* gB0 = Bt + (size_t)(n0 + rA) * K + ko;
    const u16* gB1 = Bt + (size_t)(n0 + 64 + rA) * K + ko;
    u16* lA0 = As + (size_t)t * 8;
    u16* lA1 = As + (size_t)(256 + t) * 8;
    u16* lB0 = Bs + (size_t)t * 8;
    u16* lB1 = Bs + (size_t)(256 + t) * 8;

    for (int k0 = 0; k0 < K; k0 += 32) {
        async_copy16(gA0 + k0, lA0);
        async_copy16(gA1 + k0, lA1);
        async_copy16(gB0 + k0, lB0);
        async_copy16(gB1 + k0, lB1);
        __syncthreads();
        bf16x8 af[4], bfr[4];
#pragma unroll
        for (int i = 0; i < 4; ++i)
            af[i] = *(const bf16x8*)&As[(mw + i * 16 + mr) * 32 + quad * 8];
#pragma unroll
        for (int j = 0; j < 4; ++j)
            bfr[j] = *(const bf16x8*)&Bs[(nw + j * 16 + mr) * 32 + quad * 8];
#pragma unroll
        for (int i = 0; i < 4; ++i)
#pragma unroll
            for (int j = 0; j < 4; ++j)
                acc[i][j] = __builtin_amdgcn_mfma_f32_16x16x32_bf16(af[i], bfr[j], acc[i][j], 0, 0, 0);
        __syncthreads();
    }

    if (mode == 0) {
#pragma unroll
        for (int i = 0; i < 4; ++i)
#pragma unroll
            for (int j = 0; j < 4; ++j)
#pragma unroll
                for (int r = 0; r < 4; ++r) {
                    int rg = m0 + mw + i * 16 + quad * 4 + r;
                    int cg = n0 + nw + j * 16 + mr;
                    Cout[(size_t)rg * N + cg] = acc[i][j][r];
                }
    } else {
        // one part (Q/K/V) per 128-wide n-tile; coalesced [bh][t][d] rows
        int part = n0 >> 10;
        u16* dstp = (part == 0) ? Qo : (part == 1) ? Ko : Vo;
#pragma unroll
        for (int i = 0; i < 4; ++i)
#pragma unroll
            for (int j = 0; j < 4; ++j)
#pragma unroll
                for (int r = 0; r < 4; ++r) {
                    int rg = m0 + mw + i * 16 + quad * 4 + r;   // token
                    int cg = n0 + nw + j * 16 + mr;             // qkv column
                    int cc = cg & 1023;
                    int h = cc >> 6, d = cc & 63;
                    int b = rg >> 11, tt = rg & 2047;
                    int bh = b * NHH + h;
                    dstp[((size_t)bh * TT + tt) * HDD + d] = f2bf(acc[i][j][r]);
                }
    }
}

// ---------------- flash attention v4 ----------------
// Block = 4 waves, one head, 64 q-rows (wave w -> rows q0blk+16w..+15).
// Per iter: 64-kv chunk of K and V staged into LDS (global_load_lds, XOR-swizzled),
// shared by all 4 waves. S^T orientation; wave-private P LDS; masked chunk peeled.

#define PSTRIDE 72

template<bool MASK>
__device__ __forceinline__ void attn_compute(
    const u16* __restrict__ Ks, const u16* __restrict__ Vs, u16* __restrict__ pb,
    bf16x8 qf0, bf16x8 qf1, int m, int quad, int qcol, int kv0,
    f32x4 (&o)[4], float& mi, float& li)
{
    f32x4 zero = {0.f, 0.f, 0.f, 0.f};
    const float SC = 0.125f * 1.44269504f;   // scale * log2(e)
    int sw = m & 7;
    // QK^T -> S^T: kv on quad*4+r, q on lane&15. K frags from swizzled LDS.
    f32x4 st[4];
#pragma unroll
    for (int kc = 0; kc < 4; ++kc) {
        int rr = kc * 16 + m;
        bf16x8 kf0 = *(const bf16x8*)&Ks[rr * 64 + ((quad ^ sw) << 3)];
        bf16x8 kf1 = *(const bf16x8*)&Ks[rr * 64 + (((quad + 4) ^ sw) << 3)];
        f32x4 s = __builtin_amdgcn_mfma_f32_16x16x32_bf16(kf0, qf0, zero, 0, 0, 0);
        st[kc]   = __builtin_amdgcn_mfma_f32_16x16x32_bf16(kf1, qf1, s, 0, 0, 0);
    }
    float p[16];
#pragma unroll
    for (int kc = 0; kc < 4; ++kc)
#pragma unroll
        for (int r = 0; r < 4; ++r) {
            float v = st[kc][r] * SC;
            if (MASK && (kv0 + kc * 16 + quad * 4 + r > qcol)) v = -1e30f;
            p[kc * 4 + r] = v;
        }
    float lm = fmaxf(fmaxf(fmaxf(p[0], p[1]), fmaxf(p[2], p[3])),
                     fmaxf(fmaxf(p[4], p[5]), fmaxf(p[6], p[7])));
    float lm2 = fmaxf(fmaxf(fmaxf(p[8], p[9]), fmaxf(p[10], p[11])),
                      fmaxf(fmaxf(p[12], p[13]), fmaxf(p[14], p[15])));
    lm = fmaxf(lm, lm2);
    lm = fmaxf(lm, __shfl_xor(lm, 16, 64));
    lm = fmaxf(lm, __shfl_xor(lm, 32, 64));
    float mn = fmaxf(mi, lm);
    float al = __builtin_amdgcn_exp2f(mi - mn);
    float ls = 0.f;
#pragma unroll
    for (int i = 0; i < 16; ++i) { p[i] = __builtin_amdgcn_exp2f(p[i] - mn); ls += p[i]; }
    ls += __shfl_xor(ls, 16, 64);
    ls += __shfl_xor(ls, 32, 64);
    li = li * al + ls;
    mi = mn;
#pragma unroll
    for (int dg = 0; dg < 4; ++dg) {
        f32x4 tv = o[dg];
        tv[0] *= al; tv[1] *= al; tv[2] *= al; tv[3] *= al;
        o[dg] = tv;
    }
    // P^T -> wave-private LDS [q][kv], stride 72
#pragma unroll
    for (int kc = 0; kc < 4; ++kc) {
        uint2 pk;
        pk.x = pk_bf16(p[kc * 4 + 0], p[kc * 4 + 1]);
        pk.y = pk_bf16(p[kc * 4 + 2], p[kc * 4 + 3]);
        *(uint2*)&pb[m * PSTRIDE + kc * 16 + quad * 4] = pk;
    }
    // PV: O^T += V^T-frag x P^T-frag; V frags from swizzled LDS
#pragma unroll
    for (int ks = 0; ks < 2; ++ks) {
        bf16x8 pf = *(const bf16x8*)&pb[m * PSTRIDE + ks * 32 + quad * 8];
#pragma unroll
        for (int dg = 0; dg < 4; ++dg) {
            int rr = dg * 16 + m;
            bf16x8 vfr = *(const bf16x8*)&Vs[rr * 64 + ((((quad + 4 * ks) ^ sw)) << 3)];
            o[dg] = __builtin_amdgcn_mfma_f32_16x16x32_bf16(vfr, pf, o[dg], 0, 0, 0);
        }
    }
}

__global__ __launch_bounds__(256) void attn_kernel(
    const u16* __restrict__ Q, const u16* __restrict__ K,
    const u16* __restrict__ Vt, u16* __restrict__ Y)
{
    __shared__ u16 Ks[64 * 64];
    __shared__ u16 Vs[64 * 64];
    __shared__ u16 Pl[4][16 * PSTRIDE];
    int t = threadIdx.x;
    int w = t >> 6, lane = t & 63;
    int m = lane & 15, quad = lane >> 4;

    int bid = blockIdx.x;
    int head = bid & 31;               // head&7 = XCD affinity (heuristic)
    int qb = 31 - (bid >> 5);          // heavy q-blocks first
    int q0w = qb * 64 + w * 16;

    const u16* qp = Q + ((size_t)head * TT + q0w + m) * HDD + quad * 8;
    bf16x8 qf0 = *(const bf16x8*)qp;
    bf16x8 qf1 = *(const bf16x8*)(qp + 32);

    const u16* kbase = K + (size_t)head * TT * HDD;   // [t][d]
    const u16* vbase = Vt + (size_t)head * HDD * TT;  // [d][t]
    u16* pb = &Pl[w][0];

    // staging geometry: this thread's two 16B slots (lane-contiguous LDS)
    int lr = lane >> 3;                  // 0..7
    int cg = (lane & 7) ^ lr;            // XOR swizzle on the GLOBAL col-group
    int r0 = w * 16 + lr, r1 = r0 + 8;   // rows covered: union = 0..63
    u16* ldsK0 = Ks + (size_t)(w * 128 + lane) * 8;
    u16* ldsK1 = Ks + (size_t)(w * 128 + 64 + lane) * 8;
    u16* ldsV0 = Vs + (size_t)(w * 128 + lane) * 8;
    u16* ldsV1 = Vs + (size_t)(w * 128 + 64 + lane) * 8;

    float mi = -1e30f, li = 0.f;
    f32x4 zero = {0.f, 0.f, 0.f, 0.f};
    f32x4 o[4];
#pragma unroll
    for (int dg = 0; dg < 4; ++dg) o[dg] = zero;
    int qcol = q0w + m;

    for (int ic = 0; ic < qb; ++ic) {
        int kv0 = ic << 6;
        async_copy16(kbase + (size_t)(kv0 + r0) * 64 + cg * 8, ldsK0);
        async_copy16(kbase + (size_t)(kv0 + r1) * 64 + cg * 8, ldsK1);
        async_copy16(vbase + (size_t)r0 * TT + kv0 + cg * 8, ldsV0);
        async_copy16(vbase + (size_t)r1 * TT + kv0 + cg * 8, ldsV1);
        __syncthreads();
        attn_compute<false>(Ks, Vs, pb, qf0, qf1, m, quad, qcol, kv0, o, mi, li);
        __syncthreads();
    }
    {
        int kv0 = qb << 6;
        async_copy16(kbase + (size_t)(kv0 + r0) * 64 + cg * 8, ldsK0);
        async_copy16(kbase + (size_t)(kv0 + r1) * 64 + cg * 8, ldsK1);
        async_copy16(vbase + (size_t)r0 * TT + kv0 + cg * 8, ldsV0);
        async_copy16(vbase + (size_t)r1 * TT + kv0 + cg * 8, ldsV1);
        __syncthreads();
        attn_compute<true>(Ks, Vs, pb, qf0, qf1, m, quad, qcol, kv0, o, mi, li);
    }

    // epilogue: O^T tile dg: rows d=dg*16+quad*4+r, col q=m
    float inv = 1.0f / li;
    int b = head >> 4, h = head & 15;
    int tt = q0w + m;
    size_t rowoff = ((size_t)(b * TT + tt)) * CCH + h * HDD;
#pragma unroll
    for (int dg = 0; dg < 4; ++dg) {
        uint2 ov;
        ov.x = pk_bf16(o[dg][0] * inv, o[dg][1] * inv);
        ov.y = pk_bf16(o[dg][2] * inv, o[dg][3] * inv);
        *(uint2*)&Y[rowoff + dg * 16 + quad * 4] = ov;
    }
}

// ---------------- launch ----------------

extern "C" void kernel_launch(void* const* d_in, const int* in_sizes, int n_in,
                              void* d_out, int out_size, void* d_ws, size_t ws_size,
                              hipStream_t stream) {
    const float* x      = (const float*)d_in[0];
    const float* w_attn = (const float*)d_in[1];
    const float* w_proj = (const float*)d_in[2];
    float* out = (float*)d_out;

    char* ws = (char*)d_ws;
    u16* x_bf   = (u16*)ws; ws += (size_t)M_TOK * CCH * 2;         // 8 MB
    u16* wqkvT  = (u16*)ws; ws += (size_t)N_QKV * CCH * 2;         // 6 MB
    u16* wprojT = (u16*)ws; ws += (size_t)CCH * CCH * 2;           // 2 MB
    u16* qbuf   = (u16*)ws; ws += (size_t)BB * NHH * TT * HDD * 2; // 8 MB
    u16* kbuf   = (u16*)ws; ws += (size_t)BB * NHH * TT * HDD * 2; // 8 MB
    u16* vbuf   = (u16*)ws; ws += (size_t)BB * NHH * TT * HDD * 2; // 8 MB
    u16* vtb    = (u16*)ws; ws += (size_t)BB * NHH * HDD * TT * 2; // 8 MB
    u16* yb     = (u16*)ws; ws += (size_t)M_TOK * CCH * 2;         // 8 MB

    // 1. cast x -> bf16
    cast_bf16_kernel<<<dim3(M_TOK * CCH / 4 / 256), dim3(256), 0, stream>>>(x, x_bf, M_TOK * CCH / 4);
    // 2. transpose weights -> bf16 [N][K]
    transpose_bf16_kernel<<<dim3(N_QKV / 32, CCH / 32), dim3(32, 8), 0, stream>>>(w_attn, wqkvT, CCH, N_QKV);
    transpose_bf16_kernel<<<dim3(CCH / 32, CCH / 32), dim3(32, 8), 0, stream>>>(w_proj, wprojT, CCH, CCH);
    // 3. QKV GEMM, coalesced Q/K/V rows
    gemm_bt_kernel<<<dim3(N_QKV / 128, M_TOK / 128), dim3(256), 0, stream>>>(
        x_bf, wqkvT, M_TOK, N_QKV, CCH, nullptr, qbuf, kbuf, vbuf, 1);
    // 4. V -> V^T
    transpose_v_kernel<<<dim3(TT / 32, HDD / 32, BB * NHH), dim3(32, 8), 0, stream>>>(vbuf, vtb);
    // 5. flash attention (4 waves/block share K/V LDS)
    attn_kernel<<<dim3(1024), dim3(256), 0, stream>>>(qbuf, kbuf, vtb, yb);
    // 6. output projection
    gemm_bt_kernel<<<dim3(CCH / 128, M_TOK / 128), dim3(256), 0, stream>>>(
        yb, wprojT, M_TOK, CCH, CCH, out, nullptr, nullptr, nullptr, 0);
}